// Round 1
// 579.697 us; speedup vs baseline: 1.3022x; 1.3022x over previous
//
#include <hip/hip_runtime.h>
#include <hip/hip_bf16.h>

#define HD 128
#define RNUM 8
#define SCAN_BS 2048

typedef __attribute__((ext_vector_type(8))) short short8;
typedef __attribute__((ext_vector_type(4))) float float4e;

__device__ __forceinline__ unsigned short f2bf(float f) {
    unsigned int u = __float_as_uint(f);
    u += 0x7fffu + ((u >> 16) & 1u);   // RNE
    return (unsigned short)(u >> 16);
}

// ---------------- small kernels ----------------
__global__ void zero_i(int* __restrict__ p, int n) {
    int g = blockIdx.x * blockDim.x + threadIdx.x;
    if (g < n) p[g] = 0;
}

// ---------------- CSR build: count -> scan -> fill ----------------
__global__ void count_kernel(const int* __restrict__ ei, const int* __restrict__ et,
                             int* __restrict__ cnt, int E, int N) {
    int e = blockIdx.x * blockDim.x + threadIdx.x;
    if (e < E) atomicAdd(&cnt[et[e] * N + ei[E + e]], 1);
}

__global__ void scan1(const int* __restrict__ in, int* __restrict__ out,
                      int* __restrict__ bsum, int n) {
    __shared__ int s[256];
    const int tid = threadIdx.x;
    const int base = blockIdx.x * SCAN_BS + tid * 8;
    int v[8];
    int sum = 0;
#pragma unroll
    for (int j = 0; j < 8; j++) {
        int x = (base + j < n) ? in[base + j] : 0;
        v[j] = sum;
        sum += x;
    }
    s[tid] = sum;
    __syncthreads();
    for (int off = 1; off < 256; off <<= 1) {
        int tv = (tid >= off) ? s[tid - off] : 0;
        __syncthreads();
        if (tid >= off) s[tid] += tv;
        __syncthreads();
    }
    int excl = (tid > 0) ? s[tid - 1] : 0;
    if (tid == 255) bsum[blockIdx.x] = s[255];
#pragma unroll
    for (int j = 0; j < 8; j++)
        if (base + j < n) out[base + j] = v[j] + excl;
}

__global__ void scan2(int* __restrict__ bsum, int nb) {
    __shared__ int s[512];
    const int tid = threadIdx.x;
    s[tid] = (tid < nb) ? bsum[tid] : 0;
    __syncthreads();
    for (int off = 1; off < 512; off <<= 1) {
        int tv = (tid >= off) ? s[tid - off] : 0;
        __syncthreads();
        if (tid >= off) s[tid] += tv;
        __syncthreads();
    }
    if (tid < nb) bsum[tid] = (tid > 0) ? s[tid - 1] : 0;
}

__global__ void scan3(int* __restrict__ out, int* __restrict__ cur,
                      const int* __restrict__ bsum, int n) {
    const int base = blockIdx.x * SCAN_BS + threadIdx.x * 8;
    const int add = bsum[blockIdx.x];
#pragma unroll
    for (int j = 0; j < 8; j++) {
        int i = base + j;
        if (i < n) {
            int v = out[i] + add;
            out[i] = v;
            cur[i] = v;
        }
    }
}

// fill: col = src node id (for layer 2 / fallback), colE = pre-resolved entity id
// (for layer-1 agg: removes the ids[] dependent gather from the edge loop)
__global__ void fill_kernel(const int* __restrict__ ei, const int* __restrict__ et,
                            const int* __restrict__ ids,
                            int* __restrict__ cur, int* __restrict__ col,
                            int* __restrict__ colE, int E, int N) {
    int e = blockIdx.x * blockDim.x + threadIdx.x;
    if (e < E) {
        int src = ei[e];
        int pos = atomicAdd(&cur[et[e] * N + ei[E + e]], 1);
        col[pos] = src;
        colE[pos] = ids[src];
    }
}

// ---------------- weight pre-transpose to bf16: WT[f][d] = bf16(W[d][f]) ----------------
__global__ void wt_kernel(const float* __restrict__ W, unsigned short* __restrict__ WT,
                          int nmat) {
    int g = blockIdx.x * blockDim.x + threadIdx.x;
    if (g >= nmat * 16384) return;
    int mat = g >> 14;
    int d = (g >> 7) & 127;
    int f = g & 127;
    WT[mat * 16384 + f * 128 + d] = f2bf(W[g]);
}

// ---------------- agg_chunk: bf16 panel t[cn][8*128] for dst in [c0, c0+cn) ----------------
// ONE WAVE PER DST NODE. lane: r = lane>>3 (relation), sub = lane&7 (feature block).
// Each 8-lane group aggregates one (dst, r) segment; the 8 divergent edge loops
// run concurrently under the exec mask, and the wave writes the full 2 KB panel
// row coalesced. 8x fewer waves than one-wave-per-segment.
__global__ void agg_chunk(const int* __restrict__ row_start, const int* __restrict__ col,
                          const float* __restrict__ x,
                          unsigned short* __restrict__ t, int N, int E, int c0, int cn) {
    int W = (int)(((long long)blockIdx.x * blockDim.x + threadIdx.x) >> 6);
    if (W >= cn) return;
    const int lane = threadIdx.x & 63;
    const int r = lane >> 3;
    const int sub = lane & 7;
    const int dst = c0 + W;
    const int seg = r * N + dst;
    const int s0 = row_start[seg];
    const int s1 = (seg == RNUM * N - 1) ? E : row_start[seg + 1];

    float4e a0 = {0.f, 0.f, 0.f, 0.f};
    float4e a1 = {0.f, 0.f, 0.f, 0.f};
    float4e a2 = {0.f, 0.f, 0.f, 0.f};
    float4e a3 = {0.f, 0.f, 0.f, 0.f};
    for (int e = s0; e < s1; e++) {
        int c = col[e];
        const float4e* xp = (const float4e*)(x + (size_t)c * HD + sub * 16);
        a0 += xp[0];
        a1 += xp[1];
        a2 += xp[2];
        a3 += xp[3];
    }
    const float inv = (s1 > s0) ? (1.0f / (float)(s1 - s0)) : 0.0f;
    a0 *= inv; a1 *= inv; a2 *= inv; a3 *= inv;

    uint4 o0, o1;
    o0.x = (unsigned int)f2bf(a0[0]) | ((unsigned int)f2bf(a0[1]) << 16);
    o0.y = (unsigned int)f2bf(a0[2]) | ((unsigned int)f2bf(a0[3]) << 16);
    o0.z = (unsigned int)f2bf(a1[0]) | ((unsigned int)f2bf(a1[1]) << 16);
    o0.w = (unsigned int)f2bf(a1[2]) | ((unsigned int)f2bf(a1[3]) << 16);
    o1.x = (unsigned int)f2bf(a2[0]) | ((unsigned int)f2bf(a2[1]) << 16);
    o1.y = (unsigned int)f2bf(a2[2]) | ((unsigned int)f2bf(a2[3]) << 16);
    o1.z = (unsigned int)f2bf(a3[0]) | ((unsigned int)f2bf(a3[1]) << 16);
    o1.w = (unsigned int)f2bf(a3[2]) | ((unsigned int)f2bf(a3[3]) << 16);

    unsigned short* dp = t + (size_t)W * (RNUM * HD) + r * HD + sub * 16;
    *(uint4*)dp = o0;
    *(uint4*)(dp + 8) = o1;
}

// ---------------- gemm_chunk: C[c0+m,:] = act( sum_{s<8} panel[m,s] @ W_s + x[row]@root + b ) ----------------
template <bool HAS_IDX, int ACT>   // ACT: 0 = relu, 1 = sigmoid
__launch_bounds__(256)
__global__ void gemm_chunk(const unsigned short* __restrict__ Abuf,
                           const float* __restrict__ x, const int* __restrict__ ids,
                           const unsigned short* __restrict__ WT,
                           const float* __restrict__ bias,
                           float* __restrict__ Cout, int N, int c0, int cn) {
    __shared__ unsigned short As[128 * 128];  // 32 KB
    __shared__ unsigned short Ws[128 * 128];  // 32 KB

    const int tid = threadIdx.x;
    const int block0 = blockIdx.x * 128;      // local within chunk
    const int w = tid >> 6;
    const int lane = tid & 63;
    const int ln15 = lane & 15;
    const int quad = lane >> 4;
    const int rowbase = (w & 1) * 64;
    const int colbase = (w >> 1) * 64;

    float4e acc[4][4];
#pragma unroll
    for (int i = 0; i < 4; i++)
#pragma unroll
        for (int j = 0; j < 4; j++)
#pragma unroll
            for (int q = 0; q < 4; q++) acc[i][j][q] = 0.0f;

    for (int s = 0; s < 9; s++) {
        // ---- stage A tile ----
        if (s < RNUM) {
#pragma unroll
            for (int i = 0; i < 8; i++) {
                int c = i * 256 + tid;           // chunk of 8 shorts
                int row = c >> 4;
                int ck = c & 15;
                int rl = block0 + row; if (rl >= cn) rl = cn - 1;
                uint4 v = *(const uint4*)(Abuf + (size_t)rl * (RNUM * HD) + s * HD + ck * 8);
                *(uint4*)&As[row * 128 + ((ck ^ (row & 15)) << 3)] = v;
            }
        } else {
            // root/self term straight from x (gather for layer 1)
#pragma unroll
            for (int i = 0; i < 8; i++) {
                int c = i * 256 + tid;
                int row = c >> 4;
                int ck = c & 15;
                int rl = block0 + row; if (rl >= cn) rl = cn - 1;
                int gnode = c0 + rl;
                int src = HAS_IDX ? ids[gnode] : gnode;
                const float* xp = x + (size_t)src * HD + ck * 8;
                float4 v0 = *(const float4*)(xp);
                float4 v1 = *(const float4*)(xp + 4);
                uint4 o;
                o.x = (unsigned int)f2bf(v0.x) | ((unsigned int)f2bf(v0.y) << 16);
                o.y = (unsigned int)f2bf(v0.z) | ((unsigned int)f2bf(v0.w) << 16);
                o.z = (unsigned int)f2bf(v1.x) | ((unsigned int)f2bf(v1.y) << 16);
                o.w = (unsigned int)f2bf(v1.z) | ((unsigned int)f2bf(v1.w) << 16);
                *(uint4*)&As[row * 128 + ((ck ^ (row & 15)) << 3)] = o;
            }
        }
        // ---- stage W tile ----
        {
            const unsigned short* Wsrc = WT + s * 16384;
#pragma unroll
            for (int q = 0; q < 8; q++) {
                int chunk = q * 256 + tid;
                int f = chunk >> 4;
                int c = chunk & 15;
                uint4 v = *(const uint4*)(Wsrc + chunk * 8);
                *(uint4*)&Ws[f * 128 + ((c ^ (f & 15)) << 3)] = v;
            }
        }
        __syncthreads();

#pragma unroll
        for (int k0 = 0; k0 < 4; k0++) {
            short8 af[4], bf[4];
#pragma unroll
            for (int rt = 0; rt < 4; rt++) {
                int m = rowbase + rt * 16 + ln15;
                int ck = k0 * 4 + quad;
                af[rt] = *(const short8*)&As[m * 128 + ((ck ^ (m & 15)) << 3)];
            }
#pragma unroll
            for (int ct = 0; ct < 4; ct++) {
                int n = colbase + ct * 16 + ln15;
                int ck = k0 * 4 + quad;
                bf[ct] = *(const short8*)&Ws[n * 128 + ((ck ^ (n & 15)) << 3)];
            }
#pragma unroll
            for (int rt = 0; rt < 4; rt++)
#pragma unroll
                for (int ct = 0; ct < 4; ct++)
                    acc[rt][ct] = __builtin_amdgcn_mfma_f32_16x16x32_bf16(
                        af[rt], bf[ct], acc[rt][ct], 0, 0, 0);
        }
        __syncthreads();
    }

#pragma unroll
    for (int ct = 0; ct < 4; ct++) {
        int ncol = colbase + ct * 16 + ln15;
        float bv = bias[ncol];
#pragma unroll
        for (int rt = 0; rt < 4; rt++) {
#pragma unroll
            for (int rg = 0; rg < 4; rg++) {
                int rl = block0 + rowbase + rt * 16 + quad * 4 + rg;
                if (rl < cn) {
                    float v = acc[rt][ct][rg] + bv;
                    v = (ACT == 0) ? fmaxf(v, 0.0f) : (1.0f / (1.0f + expf(-v)));
                    Cout[(size_t)(c0 + rl) * HD + ncol] = v;
                }
            }
        }
    }
}

// ---------------- fallback: R5 fused layer ----------------
template <bool HAS_IDX, int ACT>
__launch_bounds__(256)
__global__ void rgcn_layer(const int* __restrict__ row_start, const int* __restrict__ col,
                           const int* __restrict__ ids, const float* __restrict__ x,
                           const unsigned short* __restrict__ WT,
                           const float* __restrict__ bias,
                           float* __restrict__ Cout, int N, int E) {
    __shared__ unsigned short As[128 * 128];
    __shared__ unsigned short Ws[128 * 128];

    const int tid = threadIdx.x;
    const int block0 = blockIdx.x * 128;
    const int w = tid >> 6;
    const int lane = tid & 63;
    const int ln15 = lane & 15;
    const int quad = lane >> 4;
    const int rowbase = (w & 1) * 64;
    const int colbase = (w >> 1) * 64;

    float4e acc[4][4];
#pragma unroll
    for (int i = 0; i < 4; i++)
#pragma unroll
        for (int j = 0; j < 4; j++)
#pragma unroll
            for (int q = 0; q < 4; q++) acc[i][j][q] = 0.0f;

    const int srow = tid >> 5;
    const int f4 = (tid & 31) * 4;
    const int sck = f4 >> 3;

    for (int s = 0; s < 9; s++) {
        if (s < RNUM) {
#pragma unroll 1
            for (int p = 0; p < 16; p++) {
                int row = p * 8 + srow;
                int gr = block0 + row;
                float ax = 0.f, ay = 0.f, az = 0.f, aw = 0.f, inv = 0.f;
                if (gr < N) {
                    int seg = s * N + gr;
                    int s0 = row_start[seg];
                    int s1 = (seg == RNUM * N - 1) ? E : row_start[seg + 1];
                    if (s1 > s0) inv = 1.0f / (float)(s1 - s0);
                    for (int e = s0; e < s1; e++) {
                        int c = col[e];
                        if (HAS_IDX) c = ids[c];
                        float4 v = *(const float4*)(x + (size_t)c * HD + f4);
                        ax += v.x; ay += v.y; az += v.z; aw += v.w;
                    }
                }
                int si = row * 128 + ((sck ^ (row & 15)) << 3) + (f4 & 7);
                ushort4 o;
                o.x = f2bf(ax * inv); o.y = f2bf(ay * inv);
                o.z = f2bf(az * inv); o.w = f2bf(aw * inv);
                *(ushort4*)&As[si] = o;
            }
        } else {
#pragma unroll 1
            for (int p = 0; p < 16; p++) {
                int row = p * 8 + srow;
                int gr = block0 + row;
                float4 v = make_float4(0.f, 0.f, 0.f, 0.f);
                if (gr < N) {
                    int c = HAS_IDX ? ids[gr] : gr;
                    v = *(const float4*)(x + (size_t)c * HD + f4);
                }
                int si = row * 128 + ((sck ^ (row & 15)) << 3) + (f4 & 7);
                ushort4 o;
                o.x = f2bf(v.x); o.y = f2bf(v.y); o.z = f2bf(v.z); o.w = f2bf(v.w);
                *(ushort4*)&As[si] = o;
            }
        }
        {
            const unsigned short* Wsrc = WT + s * 16384;
#pragma unroll
            for (int q = 0; q < 8; q++) {
                int chunk = q * 256 + tid;
                int f = chunk >> 4;
                int c = chunk & 15;
                uint4 v = *(const uint4*)(Wsrc + chunk * 8);
                *(uint4*)&Ws[f * 128 + ((c ^ (f & 15)) << 3)] = v;
            }
        }
        __syncthreads();
#pragma unroll
        for (int k0 = 0; k0 < 4; k0++) {
            short8 af[4], bf[4];
#pragma unroll
            for (int rt = 0; rt < 4; rt++) {
                int m = rowbase + rt * 16 + ln15;
                int ck = k0 * 4 + quad;
                af[rt] = *(const short8*)&As[m * 128 + ((ck ^ (m & 15)) << 3)];
            }
#pragma unroll
            for (int ct = 0; ct < 4; ct++) {
                int n = colbase + ct * 16 + ln15;
                int ck = k0 * 4 + quad;
                bf[ct] = *(const short8*)&Ws[n * 128 + ((ck ^ (n & 15)) << 3)];
            }
#pragma unroll
            for (int rt = 0; rt < 4; rt++)
#pragma unroll
                for (int ct = 0; ct < 4; ct++)
                    acc[rt][ct] = __builtin_amdgcn_mfma_f32_16x16x32_bf16(
                        af[rt], bf[ct], acc[rt][ct], 0, 0, 0);
        }
        __syncthreads();
    }

#pragma unroll
    for (int ct = 0; ct < 4; ct++) {
        int ncol = colbase + ct * 16 + ln15;
        float bv = bias[ncol];
#pragma unroll
        for (int rt = 0; rt < 4; rt++) {
#pragma unroll
            for (int rg = 0; rg < 4; rg++) {
                int rowg = block0 + rowbase + rt * 16 + quad * 4 + rg;
                if (rowg < N) {
                    float v = acc[rt][ct][rg] + bv;
                    v = (ACT == 0) ? fmaxf(v, 0.0f) : (1.0f / (1.0f + expf(-v)));
                    Cout[(size_t)rowg * HD + ncol] = v;
                }
            }
        }
    }
}

extern "C" void kernel_launch(void* const* d_in, const int* in_sizes, int n_in,
                              void* d_out, int out_size, void* d_ws, size_t ws_size,
                              hipStream_t stream) {
    const int*   x_ids = (const int*)d_in[0];
    const int*   ei    = (const int*)d_in[1];
    const int*   et    = (const int*)d_in[2];
    const float* emb   = (const float*)d_in[3];
    const float* W1    = (const float*)d_in[4];
    const float* root1 = (const float*)d_in[5];
    const float* b1    = (const float*)d_in[6];
    const float* W2    = (const float*)d_in[7];
    const float* root2 = (const float*)d_in[8];
    const float* b2    = (const float*)d_in[9];

    const int N = in_sizes[0];
    const int E = in_sizes[1] / 2;
    const int NS = RNUM * N;
    float* out = (float*)d_out;

    // ---- fixed arenas (~59 MB), then panel (aliases cur: cur only used in CSR build) ----
    char* ws = (char*)d_ws;
    size_t off = 0;
    int* row_start = (int*)(ws + off); off += (size_t)NS * 4;                 // 3.2 MB
    int* col       = (int*)(ws + off); off += (size_t)E * 4;                  // 2.0 MB
    int* colE      = (int*)(ws + off); off += (size_t)E * 4;                  // 2.0 MB
    int* bsum      = (int*)(ws + off); off += 4096;
    unsigned short* WT = (unsigned short*)(ws + off); off += (size_t)18 * 16384 * 2;
    float* z       = (float*)(ws + off); off += (size_t)N * HD * 4;           // 51.2 MB
    int* cur       = (int*)(ws + off);                                        // CSR build only
    unsigned short* panel = (unsigned short*)(ws + off);                      // aliases cur

    size_t avail = (ws_size > off) ? (ws_size - off) : 0;
    // cur needs NS*4 bytes; panel needs CH*2048 bytes. Both must fit in avail.
    long long CH_ll = (long long)(avail / (RNUM * HD * 2));
    if (CH_ll > N) CH_ll = N;
    int CH = (int)(CH_ll & ~127LL);     // multiple of 128
    bool ok = (avail >= (size_t)NS * 4) && (CH >= 2048);

    const int scanBlocks = (NS + SCAN_BS - 1) / SCAN_BS;
    const int layerGrid = (N + 127) / 128;

    // ---- CSR build ----
    zero_i<<<(NS + 255) / 256, 256, 0, stream>>>(cur, NS);
    count_kernel<<<(E + 255) / 256, 256, 0, stream>>>(ei, et, cur, E, N);
    scan1<<<scanBlocks, 256, 0, stream>>>(cur, row_start, bsum, NS);
    scan2<<<1, 512, 0, stream>>>(bsum, scanBlocks);
    scan3<<<scanBlocks, 256, 0, stream>>>(row_start, cur, bsum, NS);
    fill_kernel<<<(E + 255) / 256, 256, 0, stream>>>(ei, et, x_ids, cur, col, colE, E, N);

    // ---- weights -> bf16 transposed: layer1 [0..8], layer2 [9..17] ----
    wt_kernel<<<(8 * 16384 + 255) / 256, 256, 0, stream>>>(W1, WT, 8);
    wt_kernel<<<(1 * 16384 + 255) / 256, 256, 0, stream>>>(root1, WT + 8 * 16384, 1);
    wt_kernel<<<(8 * 16384 + 255) / 256, 256, 0, stream>>>(W2, WT + 9 * 16384, 8);
    wt_kernel<<<(1 * 16384 + 255) / 256, 256, 0, stream>>>(root2, WT + 17 * 16384, 1);

    if (ok) {
        // ---- layer 1: z = relu(agg(emb[ids]) + emb[ids]@root1 + b1) ----
        for (int c0 = 0; c0 < N; c0 += CH) {
            int cn = (N - c0 < CH) ? (N - c0) : CH;
            int aggGrid = (cn * 64 + 255) / 256;          // one wave per dst
            agg_chunk<<<aggGrid, 256, 0, stream>>>(row_start, colE, emb,
                                                   panel, N, E, c0, cn);
            gemm_chunk<true, 0><<<(cn + 127) / 128, 256, 0, stream>>>(
                panel, emb, x_ids, WT, b1, z, N, c0, cn);
        }
        // ---- layer 2: out = sigmoid(agg(z) + z@root2 + b2) ----
        for (int c0 = 0; c0 < N; c0 += CH) {
            int cn = (N - c0 < CH) ? (N - c0) : CH;
            int aggGrid = (cn * 64 + 255) / 256;
            agg_chunk<<<aggGrid, 256, 0, stream>>>(row_start, col, z,
                                                   panel, N, E, c0, cn);
            gemm_chunk<false, 1><<<(cn + 127) / 128, 256, 0, stream>>>(
                panel, z, nullptr, WT + 9 * 16384, b2, out, N, c0, cn);
        }
    } else {
        rgcn_layer<true, 0><<<layerGrid, 256, 0, stream>>>(
            row_start, col, x_ids, emb, WT, b1, z, N, E);
        rgcn_layer<false, 1><<<layerGrid, 256, 0, stream>>>(
            row_start, col, nullptr, z, WT + 9 * 16384, b2, out, N, E);
    }
}

// Round 2
// 511.103 us; speedup vs baseline: 1.4770x; 1.1342x over previous
//
#include <hip/hip_runtime.h>
#include <hip/hip_bf16.h>

#define HD 128
#define RNUM 8
#define SCAN_BS 2048
#define CH_MAX 49152   // panel buffer 100 MB -> chunk working set stays L3-resident

typedef __attribute__((ext_vector_type(8))) short short8;
typedef __attribute__((ext_vector_type(4))) float float4e;

__device__ __forceinline__ unsigned short f2bf(float f) {
    unsigned int u = __float_as_uint(f);
    u += 0x7fffu + ((u >> 16) & 1u);   // RNE
    return (unsigned short)(u >> 16);
}

__device__ __forceinline__ void gload_lds16(const void* g, void* l) {
    __builtin_amdgcn_global_load_lds(
        (const __attribute__((address_space(1))) void*)g,
        (__attribute__((address_space(3))) void*)l, 16, 0, 0);
}

// ---------------- small kernels ----------------
__global__ void zero_i(int* __restrict__ p, int n) {
    int g = blockIdx.x * blockDim.x + threadIdx.x;
    if (g < n) p[g] = 0;
}

// ---------------- CSR build: count -> scan -> fill ----------------
__global__ void count_kernel(const int* __restrict__ ei, const int* __restrict__ et,
                             int* __restrict__ cnt, int E, int N) {
    int e = blockIdx.x * blockDim.x + threadIdx.x;
    if (e < E) atomicAdd(&cnt[et[e] * N + ei[E + e]], 1);
}

__global__ void scan1(const int* __restrict__ in, int* __restrict__ out,
                      int* __restrict__ bsum, int n) {
    __shared__ int s[256];
    const int tid = threadIdx.x;
    const int base = blockIdx.x * SCAN_BS + tid * 8;
    int v[8];
    int sum = 0;
#pragma unroll
    for (int j = 0; j < 8; j++) {
        int x = (base + j < n) ? in[base + j] : 0;
        v[j] = sum;
        sum += x;
    }
    s[tid] = sum;
    __syncthreads();
    for (int off = 1; off < 256; off <<= 1) {
        int tv = (tid >= off) ? s[tid - off] : 0;
        __syncthreads();
        if (tid >= off) s[tid] += tv;
        __syncthreads();
    }
    int excl = (tid > 0) ? s[tid - 1] : 0;
    if (tid == 255) bsum[blockIdx.x] = s[255];
#pragma unroll
    for (int j = 0; j < 8; j++)
        if (base + j < n) out[base + j] = v[j] + excl;
}

__global__ void scan2(int* __restrict__ bsum, int nb) {
    __shared__ int s[512];
    const int tid = threadIdx.x;
    s[tid] = (tid < nb) ? bsum[tid] : 0;
    __syncthreads();
    for (int off = 1; off < 512; off <<= 1) {
        int tv = (tid >= off) ? s[tid - off] : 0;
        __syncthreads();
        if (tid >= off) s[tid] += tv;
        __syncthreads();
    }
    if (tid < nb) bsum[tid] = (tid > 0) ? s[tid - 1] : 0;
}

__global__ void scan3(int* __restrict__ out, int* __restrict__ cur,
                      const int* __restrict__ bsum, int n) {
    const int base = blockIdx.x * SCAN_BS + threadIdx.x * 8;
    const int add = bsum[blockIdx.x];
#pragma unroll
    for (int j = 0; j < 8; j++) {
        int i = base + j;
        if (i < n) {
            int v = out[i] + add;
            out[i] = v;
            cur[i] = v;
        }
    }
}

// fill: col = src node id (layer 2 / fallback), colE = pre-resolved entity id (layer 1)
__global__ void fill_kernel(const int* __restrict__ ei, const int* __restrict__ et,
                            const int* __restrict__ ids,
                            int* __restrict__ cur, int* __restrict__ col,
                            int* __restrict__ colE, int E, int N) {
    int e = blockIdx.x * blockDim.x + threadIdx.x;
    if (e < E) {
        int src = ei[e];
        int pos = atomicAdd(&cur[et[e] * N + ei[E + e]], 1);
        col[pos] = src;
        colE[pos] = ids[src];
    }
}

// ---------------- weight pre-transpose to bf16: WT[f][d] = bf16(W[d][f]) ----------------
__global__ void wt_kernel(const float* __restrict__ W, unsigned short* __restrict__ WT,
                          int nmat) {
    int g = blockIdx.x * blockDim.x + threadIdx.x;
    if (g >= nmat * 16384) return;
    int mat = g >> 14;
    int d = (g >> 7) & 127;
    int f = g & 127;
    WT[mat * 16384 + f * 128 + d] = f2bf(W[g]);
}

// ---------------- agg_chunk: bf16 panel t[cn][8*128] for dst in [c0, c0+cn) ----------------
// ONE WAVE PER DST NODE; 8-lane group per relation.
__global__ void agg_chunk(const int* __restrict__ row_start, const int* __restrict__ col,
                          const float* __restrict__ x,
                          unsigned short* __restrict__ t, int N, int E, int c0, int cn) {
    int W = (int)(((long long)blockIdx.x * blockDim.x + threadIdx.x) >> 6);
    if (W >= cn) return;
    const int lane = threadIdx.x & 63;
    const int r = lane >> 3;
    const int sub = lane & 7;
    const int dst = c0 + W;
    const int seg = r * N + dst;
    const int s0 = row_start[seg];
    const int s1 = (seg == RNUM * N - 1) ? E : row_start[seg + 1];

    float4e a0 = {0.f, 0.f, 0.f, 0.f};
    float4e a1 = {0.f, 0.f, 0.f, 0.f};
    float4e a2 = {0.f, 0.f, 0.f, 0.f};
    float4e a3 = {0.f, 0.f, 0.f, 0.f};
    for (int e = s0; e < s1; e++) {
        int c = col[e];
        const float4e* xp = (const float4e*)(x + (size_t)c * HD + sub * 16);
        a0 += xp[0];
        a1 += xp[1];
        a2 += xp[2];
        a3 += xp[3];
    }
    const float inv = (s1 > s0) ? (1.0f / (float)(s1 - s0)) : 0.0f;
    a0 *= inv; a1 *= inv; a2 *= inv; a3 *= inv;

    uint4 o0, o1;
    o0.x = (unsigned int)f2bf(a0[0]) | ((unsigned int)f2bf(a0[1]) << 16);
    o0.y = (unsigned int)f2bf(a0[2]) | ((unsigned int)f2bf(a0[3]) << 16);
    o0.z = (unsigned int)f2bf(a1[0]) | ((unsigned int)f2bf(a1[1]) << 16);
    o0.w = (unsigned int)f2bf(a1[2]) | ((unsigned int)f2bf(a1[3]) << 16);
    o1.x = (unsigned int)f2bf(a2[0]) | ((unsigned int)f2bf(a2[1]) << 16);
    o1.y = (unsigned int)f2bf(a2[2]) | ((unsigned int)f2bf(a2[3]) << 16);
    o1.z = (unsigned int)f2bf(a3[0]) | ((unsigned int)f2bf(a3[1]) << 16);
    o1.w = (unsigned int)f2bf(a3[2]) | ((unsigned int)f2bf(a3[3]) << 16);

    unsigned short* dp = t + (size_t)W * (RNUM * HD) + r * HD + sub * 16;
    *(uint4*)dp = o0;
    *(uint4*)(dp + 8) = o1;
}

// ---------------- gemm_chunk: 512 threads, 8 waves (2x4 grid of 64x32 sub-tiles) ------------
// A/W staged via global_load_lds (linear LDS dest, pre-XOR-swizzled global source).
template <bool HAS_IDX, int ACT>   // ACT: 0 = relu, 1 = sigmoid
__launch_bounds__(512, 4)
__global__ void gemm_chunk(const unsigned short* __restrict__ Abuf,
                           const float* __restrict__ x, const int* __restrict__ ids,
                           const unsigned short* __restrict__ WT,
                           const float* __restrict__ bias,
                           float* __restrict__ Cout, int N, int c0, int cn) {
    __shared__ unsigned short As[128 * 128];  // 32 KB
    __shared__ unsigned short Ws[128 * 128];  // 32 KB

    const int tid = threadIdx.x;
    const int block0 = blockIdx.x * 128;      // local within chunk
    const int w = tid >> 6;
    const int lane = tid & 63;
    const int ln15 = lane & 15;
    const int quad = lane >> 4;
    const int rowbase = (w & 1) * 64;         // 2 row strips of 64
    const int colbase = (w >> 1) * 32;        // 4 col strips of 32

    float4e acc[4][2];
#pragma unroll
    for (int i = 0; i < 4; i++)
#pragma unroll
        for (int j = 0; j < 2; j++)
#pragma unroll
            for (int q = 0; q < 4; q++) acc[i][j][q] = 0.0f;

    for (int s = 0; s < 9; s++) {
        // ---- stage A tile (2048 chunks of 16B; 4 per thread) ----
        if (s < RNUM) {
#pragma unroll
            for (int i = 0; i < 4; i++) {
                int c = i * 512 + tid;
                int row = c >> 4;
                int ck = c & 15;
                int rl = block0 + row; if (rl >= cn) rl = cn - 1;
                const void* src = (const void*)(Abuf + (size_t)rl * (RNUM * HD) + s * HD
                                                + ((ck ^ (row & 15)) << 3));
                int cbase = i * 512 + (tid & ~63);   // wave-uniform
                gload_lds16(src, (char*)As + (size_t)cbase * 16);
            }
        } else {
            // root/self term straight from x (gather for layer 1), register path
#pragma unroll
            for (int i = 0; i < 4; i++) {
                int c = i * 512 + tid;
                int row = c >> 4;
                int ck = c & 15;
                int rl = block0 + row; if (rl >= cn) rl = cn - 1;
                int gnode = c0 + rl;
                int src = HAS_IDX ? ids[gnode] : gnode;
                const float* xp = x + (size_t)src * HD + ck * 8;
                float4 v0 = *(const float4*)(xp);
                float4 v1 = *(const float4*)(xp + 4);
                uint4 o;
                o.x = (unsigned int)f2bf(v0.x) | ((unsigned int)f2bf(v0.y) << 16);
                o.y = (unsigned int)f2bf(v0.z) | ((unsigned int)f2bf(v0.w) << 16);
                o.z = (unsigned int)f2bf(v1.x) | ((unsigned int)f2bf(v1.y) << 16);
                o.w = (unsigned int)f2bf(v1.z) | ((unsigned int)f2bf(v1.w) << 16);
                *(uint4*)&As[row * 128 + ((ck ^ (row & 15)) << 3)] = o;
            }
        }
        // ---- stage W tile ----
        {
            const unsigned short* Wsrc = WT + s * 16384;
#pragma unroll
            for (int i = 0; i < 4; i++) {
                int c = i * 512 + tid;
                int f = c >> 4;
                int cc = c & 15;
                const void* src = (const void*)(Wsrc + f * 128 + ((cc ^ (f & 15)) << 3));
                int cbase = i * 512 + (tid & ~63);
                gload_lds16(src, (char*)Ws + (size_t)cbase * 16);
            }
        }
        __syncthreads();

#pragma unroll
        for (int k0 = 0; k0 < 4; k0++) {
            short8 af[4], bf[2];
#pragma unroll
            for (int rt = 0; rt < 4; rt++) {
                int m = rowbase + rt * 16 + ln15;
                int ck = k0 * 4 + quad;
                af[rt] = *(const short8*)&As[m * 128 + ((ck ^ (m & 15)) << 3)];
            }
#pragma unroll
            for (int ct = 0; ct < 2; ct++) {
                int n = colbase + ct * 16 + ln15;
                int ck = k0 * 4 + quad;
                bf[ct] = *(const short8*)&Ws[n * 128 + ((ck ^ (n & 15)) << 3)];
            }
#pragma unroll
            for (int rt = 0; rt < 4; rt++)
#pragma unroll
                for (int ct = 0; ct < 2; ct++)
                    acc[rt][ct] = __builtin_amdgcn_mfma_f32_16x16x32_bf16(
                        af[rt], bf[ct], acc[rt][ct], 0, 0, 0);
        }
        __syncthreads();
    }

#pragma unroll
    for (int ct = 0; ct < 2; ct++) {
        int ncol = colbase + ct * 16 + ln15;
        float bv = bias[ncol];
#pragma unroll
        for (int rt = 0; rt < 4; rt++) {
#pragma unroll
            for (int rg = 0; rg < 4; rg++) {
                int rl = block0 + rowbase + rt * 16 + quad * 4 + rg;
                if (rl < cn) {
                    float v = acc[rt][ct][rg] + bv;
                    v = (ACT == 0) ? fmaxf(v, 0.0f) : (1.0f / (1.0f + expf(-v)));
                    Cout[(size_t)(c0 + rl) * HD + ncol] = v;
                }
            }
        }
    }
}

// ---------------- fallback: fused layer (only if workspace too small) ----------------
template <bool HAS_IDX, int ACT>
__launch_bounds__(256)
__global__ void rgcn_layer(const int* __restrict__ row_start, const int* __restrict__ col,
                           const int* __restrict__ ids, const float* __restrict__ x,
                           const unsigned short* __restrict__ WT,
                           const float* __restrict__ bias,
                           float* __restrict__ Cout, int N, int E) {
    __shared__ unsigned short As[128 * 128];
    __shared__ unsigned short Ws[128 * 128];

    const int tid = threadIdx.x;
    const int block0 = blockIdx.x * 128;
    const int w = tid >> 6;
    const int lane = tid & 63;
    const int ln15 = lane & 15;
    const int quad = lane >> 4;
    const int rowbase = (w & 1) * 64;
    const int colbase = (w >> 1) * 64;

    float4e acc[4][4];
#pragma unroll
    for (int i = 0; i < 4; i++)
#pragma unroll
        for (int j = 0; j < 4; j++)
#pragma unroll
            for (int q = 0; q < 4; q++) acc[i][j][q] = 0.0f;

    const int srow = tid >> 5;
    const int f4 = (tid & 31) * 4;
    const int sck = f4 >> 3;

    for (int s = 0; s < 9; s++) {
        if (s < RNUM) {
#pragma unroll 1
            for (int p = 0; p < 16; p++) {
                int row = p * 8 + srow;
                int gr = block0 + row;
                float ax = 0.f, ay = 0.f, az = 0.f, aw = 0.f, inv = 0.f;
                if (gr < N) {
                    int seg = s * N + gr;
                    int s0 = row_start[seg];
                    int s1 = (seg == RNUM * N - 1) ? E : row_start[seg + 1];
                    if (s1 > s0) inv = 1.0f / (float)(s1 - s0);
                    for (int e = s0; e < s1; e++) {
                        int c = col[e];
                        if (HAS_IDX) c = ids[c];
                        float4 v = *(const float4*)(x + (size_t)c * HD + f4);
                        ax += v.x; ay += v.y; az += v.z; aw += v.w;
                    }
                }
                int si = row * 128 + ((sck ^ (row & 15)) << 3) + (f4 & 7);
                ushort4 o;
                o.x = f2bf(ax * inv); o.y = f2bf(ay * inv);
                o.z = f2bf(az * inv); o.w = f2bf(aw * inv);
                *(ushort4*)&As[si] = o;
            }
        } else {
#pragma unroll 1
            for (int p = 0; p < 16; p++) {
                int row = p * 8 + srow;
                int gr = block0 + row;
                float4 v = make_float4(0.f, 0.f, 0.f, 0.f);
                if (gr < N) {
                    int c = HAS_IDX ? ids[gr] : gr;
                    v = *(const float4*)(x + (size_t)c * HD + f4);
                }
                int si = row * 128 + ((sck ^ (row & 15)) << 3) + (f4 & 7);
                ushort4 o;
                o.x = f2bf(v.x); o.y = f2bf(v.y); o.z = f2bf(v.z); o.w = f2bf(v.w);
                *(ushort4*)&As[si] = o;
            }
        }
        {
            const unsigned short* Wsrc = WT + s * 16384;
#pragma unroll
            for (int q = 0; q < 8; q++) {
                int chunk = q * 256 + tid;
                int f = chunk >> 4;
                int c = chunk & 15;
                uint4 v = *(const uint4*)(Wsrc + chunk * 8);
                *(uint4*)&Ws[f * 128 + ((c ^ (f & 15)) << 3)] = v;
            }
        }
        __syncthreads();
#pragma unroll
        for (int k0 = 0; k0 < 4; k0++) {
            short8 af[4], bf[4];
#pragma unroll
            for (int rt = 0; rt < 4; rt++) {
                int m = rowbase + rt * 16 + ln15;
                int ck = k0 * 4 + quad;
                af[rt] = *(const short8*)&As[m * 128 + ((ck ^ (m & 15)) << 3)];
            }
#pragma unroll
            for (int ct = 0; ct < 4; ct++) {
                int n = colbase + ct * 16 + ln15;
                int ck = k0 * 4 + quad;
                bf[ct] = *(const short8*)&Ws[n * 128 + ((ck ^ (n & 15)) << 3)];
            }
#pragma unroll
            for (int rt = 0; rt < 4; rt++)
#pragma unroll
                for (int ct = 0; ct < 4; ct++)
                    acc[rt][ct] = __builtin_amdgcn_mfma_f32_16x16x32_bf16(
                        af[rt], bf[ct], acc[rt][ct], 0, 0, 0);
        }
        __syncthreads();
    }

#pragma unroll
    for (int ct = 0; ct < 4; ct++) {
        int ncol = colbase + ct * 16 + ln15;
        float bv = bias[ncol];
#pragma unroll
        for (int rt = 0; rt < 4; rt++) {
#pragma unroll
            for (int rg = 0; rg < 4; rg++) {
                int rowg = block0 + rowbase + rt * 16 + quad * 4 + rg;
                if (rowg < N) {
                    float v = acc[rt][ct][rg] + bv;
                    v = (ACT == 0) ? fmaxf(v, 0.0f) : (1.0f / (1.0f + expf(-v)));
                    Cout[(size_t)rowg * HD + ncol] = v;
                }
            }
        }
    }
}

extern "C" void kernel_launch(void* const* d_in, const int* in_sizes, int n_in,
                              void* d_out, int out_size, void* d_ws, size_t ws_size,
                              hipStream_t stream) {
    const int*   x_ids = (const int*)d_in[0];
    const int*   ei    = (const int*)d_in[1];
    const int*   et    = (const int*)d_in[2];
    const float* emb   = (const float*)d_in[3];
    const float* W1    = (const float*)d_in[4];
    const float* root1 = (const float*)d_in[5];
    const float* b1    = (const float*)d_in[6];
    const float* W2    = (const float*)d_in[7];
    const float* root2 = (const float*)d_in[8];
    const float* b2    = (const float*)d_in[9];

    const int N = in_sizes[0];
    const int E = in_sizes[1] / 2;
    const int NS = RNUM * N;
    float* out = (float*)d_out;

    // ---- fixed arenas, then panel (aliases cur: cur only used in CSR build) ----
    char* ws = (char*)d_ws;
    size_t off = 0;
    int* row_start = (int*)(ws + off); off += (size_t)NS * 4;                 // 3.2 MB
    int* col       = (int*)(ws + off); off += (size_t)E * 4;                  // 2.0 MB
    int* colE      = (int*)(ws + off); off += (size_t)E * 4;                  // 2.0 MB
    int* bsum      = (int*)(ws + off); off += 4096;
    unsigned short* WT = (unsigned short*)(ws + off); off += (size_t)18 * 16384 * 2;
    float* z       = (float*)(ws + off); off += (size_t)N * HD * 4;           // 51.2 MB
    int* cur       = (int*)(ws + off);                                        // CSR build only
    unsigned short* panel = (unsigned short*)(ws + off);                      // aliases cur

    size_t avail = (ws_size > off) ? (ws_size - off) : 0;
    long long CH_ll = (long long)(avail / (RNUM * HD * 2));
    if (CH_ll > N) CH_ll = N;
    int CH = (int)(CH_ll & ~127LL);     // multiple of 128
    if (CH > CH_MAX) CH = CH_MAX;       // keep panel chunk L3-resident
    bool ok = (avail >= (size_t)NS * 4) && (CH >= 2048);

    const int scanBlocks = (NS + SCAN_BS - 1) / SCAN_BS;
    const int layerGrid = (N + 127) / 128;

    // ---- CSR build ----
    zero_i<<<(NS + 255) / 256, 256, 0, stream>>>(cur, NS);
    count_kernel<<<(E + 255) / 256, 256, 0, stream>>>(ei, et, cur, E, N);
    scan1<<<scanBlocks, 256, 0, stream>>>(cur, row_start, bsum, NS);
    scan2<<<1, 512, 0, stream>>>(bsum, scanBlocks);
    scan3<<<scanBlocks, 256, 0, stream>>>(row_start, cur, bsum, NS);
    fill_kernel<<<(E + 255) / 256, 256, 0, stream>>>(ei, et, x_ids, cur, col, colE, E, N);

    // ---- weights -> bf16 transposed: layer1 [0..8], layer2 [9..17] ----
    wt_kernel<<<(8 * 16384 + 255) / 256, 256, 0, stream>>>(W1, WT, 8);
    wt_kernel<<<(1 * 16384 + 255) / 256, 256, 0, stream>>>(root1, WT + 8 * 16384, 1);
    wt_kernel<<<(8 * 16384 + 255) / 256, 256, 0, stream>>>(W2, WT + 9 * 16384, 8);
    wt_kernel<<<(1 * 16384 + 255) / 256, 256, 0, stream>>>(root2, WT + 17 * 16384, 1);

    if (ok) {
        // ---- layer 1: z = relu(agg(emb[ids]) + emb[ids]@root1 + b1) ----
        for (int c0 = 0; c0 < N; c0 += CH) {
            int cn = (N - c0 < CH) ? (N - c0) : CH;
            int aggGrid = (cn * 64 + 255) / 256;          // one wave per dst
            agg_chunk<<<aggGrid, 256, 0, stream>>>(row_start, colE, emb,
                                                   panel, N, E, c0, cn);
            gemm_chunk<true, 0><<<(cn + 127) / 128, 512, 0, stream>>>(
                panel, emb, x_ids, WT, b1, z, N, c0, cn);
        }
        // ---- layer 2: out = sigmoid(agg(z) + z@root2 + b2) ----
        for (int c0 = 0; c0 < N; c0 += CH) {
            int cn = (N - c0 < CH) ? (N - c0) : CH;
            int aggGrid = (cn * 64 + 255) / 256;
            agg_chunk<<<aggGrid, 256, 0, stream>>>(row_start, col, z,
                                                   panel, N, E, c0, cn);
            gemm_chunk<false, 1><<<(cn + 127) / 128, 512, 0, stream>>>(
                panel, z, nullptr, WT + 9 * 16384, b2, out, N, c0, cn);
        }
    } else {
        rgcn_layer<true, 0><<<layerGrid, 256, 0, stream>>>(
            row_start, col, x_ids, emb, WT, b1, z, N, E);
        rgcn_layer<false, 1><<<layerGrid, 256, 0, stream>>>(
            row_start, col, nullptr, z, WT + 9 * 16384, b2, out, N, E);
    }
}

// Round 4
// 439.109 us; speedup vs baseline: 1.7192x; 1.1640x over previous
//
#include <hip/hip_runtime.h>
#include <hip/hip_bf16.h>

#define HD 128
#define RNUM 8
#define SCAN_BS 2048

typedef __attribute__((ext_vector_type(8))) short short8;
typedef __attribute__((ext_vector_type(4))) float float4e;

__device__ __forceinline__ unsigned short f2bf(float f) {
    unsigned int u = __float_as_uint(f);
    u += 0x7fffu + ((u >> 16) & 1u);   // RNE
    return (unsigned short)(u >> 16);
}

__device__ __forceinline__ void gload_lds16(const void* g, void* l) {
    __builtin_amdgcn_global_load_lds(
        (const __attribute__((address_space(1))) void*)g,
        (__attribute__((address_space(3))) void*)l, 16, 0, 0);
}

// ---------------- small kernels ----------------
__global__ void zero_i(int* __restrict__ p, int n) {
    int g = blockIdx.x * blockDim.x + threadIdx.x;
    if (g < n) p[g] = 0;
}

// ---------------- CSR build: count -> scan -> fill ----------------
__global__ void count_kernel(const int* __restrict__ ei, const int* __restrict__ et,
                             int* __restrict__ cnt, int E, int N) {
    int e = blockIdx.x * blockDim.x + threadIdx.x;
    if (e < E) atomicAdd(&cnt[et[e] * N + ei[E + e]], 1);
}

__global__ void scan1(const int* __restrict__ in, int* __restrict__ out,
                      int* __restrict__ bsum, int n) {
    __shared__ int s[256];
    const int tid = threadIdx.x;
    const int base = blockIdx.x * SCAN_BS + tid * 8;
    int v[8];
    int sum = 0;
#pragma unroll
    for (int j = 0; j < 8; j++) {
        int x = (base + j < n) ? in[base + j] : 0;
        v[j] = sum;
        sum += x;
    }
    s[tid] = sum;
    __syncthreads();
    for (int off = 1; off < 256; off <<= 1) {
        int tv = (tid >= off) ? s[tid - off] : 0;
        __syncthreads();
        if (tid >= off) s[tid] += tv;
        __syncthreads();
    }
    int excl = (tid > 0) ? s[tid - 1] : 0;
    if (tid == 255) bsum[blockIdx.x] = s[255];
#pragma unroll
    for (int j = 0; j < 8; j++)
        if (base + j < n) out[base + j] = v[j] + excl;
}

__global__ void scan2(int* __restrict__ bsum, int nb) {
    __shared__ int s[512];
    const int tid = threadIdx.x;
    s[tid] = (tid < nb) ? bsum[tid] : 0;
    __syncthreads();
    for (int off = 1; off < 512; off <<= 1) {
        int tv = (tid >= off) ? s[tid - off] : 0;
        __syncthreads();
        if (tid >= off) s[tid] += tv;
        __syncthreads();
    }
    if (tid < nb) bsum[tid] = (tid > 0) ? s[tid - 1] : 0;
}

__global__ void scan3(int* __restrict__ out, int* __restrict__ cur,
                      const int* __restrict__ bsum, int n) {
    const int base = blockIdx.x * SCAN_BS + threadIdx.x * 8;
    const int add = bsum[blockIdx.x];
#pragma unroll
    for (int j = 0; j < 8; j++) {
        int i = base + j;
        if (i < n) {
            int v = out[i] + add;
            out[i] = v;
            cur[i] = v;
        }
    }
}

// fill: col = src node id (layer 2), colE = pre-resolved entity id (layer 1)
__global__ void fill_kernel(const int* __restrict__ ei, const int* __restrict__ et,
                            const int* __restrict__ ids,
                            int* __restrict__ cur, int* __restrict__ col,
                            int* __restrict__ colE, int E, int N) {
    int e = blockIdx.x * blockDim.x + threadIdx.x;
    if (e < E) {
        int src = ei[e];
        int pos = atomicAdd(&cur[et[e] * N + ei[E + e]], 1);
        col[pos] = src;
        colE[pos] = ids[src];
    }
}

// ---------------- weight pre-transpose to bf16: WT[f][d] = bf16(W[d][f]) ----------------
__global__ void wt_kernel(const float* __restrict__ W, unsigned short* __restrict__ WT,
                          int nmat) {
    int g = blockIdx.x * blockDim.x + threadIdx.x;
    if (g >= nmat * 16384) return;
    int mat = g >> 14;
    int d = (g >> 7) & 127;
    int f = g & 127;
    WT[mat * 16384 + f * 128 + d] = f2bf(W[g]);
}

// ---------------- fused layer: agg-into-LDS + MFMA, no panel round-trip ----------------
// 512 threads = 8 waves. Per relation s: stage Ws(s) async via global_load_lds,
// aggregate the 128x128 bf16 A-tile directly into LDS (one 8-lane group per row,
// 2 rows per group, single edge walk, 16 features/lane), barrier, MFMA, barrier.
template <bool HAS_IDX, int ACT>   // ACT: 0 = relu, 1 = sigmoid
__launch_bounds__(512, 4)
__global__ void rgcn_fused(const int* __restrict__ row_start, const int* __restrict__ col,
                           const int* __restrict__ ids, const float* __restrict__ x,
                           const unsigned short* __restrict__ WT,
                           const float* __restrict__ bias,
                           float* __restrict__ Cout, int N, int E) {
    __shared__ unsigned short As[128 * 128];  // 32 KB
    __shared__ unsigned short Ws[128 * 128];  // 32 KB

    const int tid = threadIdx.x;
    const int block0 = blockIdx.x * 128;
    // MFMA mapping (8 waves: 2 row strips x 4 col strips)
    const int w = tid >> 6;
    const int lane = tid & 63;
    const int ln15 = lane & 15;
    const int quad = lane >> 4;
    const int rowbase = (w & 1) * 64;
    const int colbase = (w >> 1) * 32;
    // agg mapping: 64 groups of 8 lanes; group g does rows {g, g+64}
    const int grp = tid >> 3;
    const int sub8 = tid & 7;

    float4e acc[4][2];
#pragma unroll
    for (int i = 0; i < 4; i++)
#pragma unroll
        for (int j = 0; j < 2; j++)
#pragma unroll
            for (int q = 0; q < 4; q++) acc[i][j][q] = 0.0f;

    for (int s = 0; s < 9; s++) {
        // ---- stage Ws(s): async DMA, overlaps the agg phase below ----
        {
            const unsigned short* Wsrc = WT + s * 16384;
#pragma unroll
            for (int i = 0; i < 4; i++) {
                int c = i * 512 + tid;
                int f = c >> 4;
                int cc = c & 15;
                const void* src = (const void*)(Wsrc + f * 128 + ((cc ^ (f & 15)) << 3));
                int cbase = i * 512 + (tid & ~63);   // wave-uniform base, lane*16 stride
                gload_lds16(src, (char*)Ws + (size_t)cbase * 16);
            }
        }
        // ---- aggregate A-tile into LDS (single edge walk, 16 feat/lane) ----
        if (s < RNUM) {
#pragma unroll 1
            for (int half = 0; half < 2; half++) {
                const int row = grp + half * 64;
                const int dst = block0 + row;
                float4e a0 = {0.f, 0.f, 0.f, 0.f};
                float4e a1 = {0.f, 0.f, 0.f, 0.f};
                float4e a2 = {0.f, 0.f, 0.f, 0.f};
                float4e a3 = {0.f, 0.f, 0.f, 0.f};
                float inv = 0.f;
                if (dst < N) {
                    int seg = s * N + dst;
                    int s0 = row_start[seg];
                    int s1 = (seg == RNUM * N - 1) ? E : row_start[seg + 1];
                    if (s1 > s0) inv = 1.0f / (float)(s1 - s0);
                    for (int e = s0; e < s1; e++) {
                        int c = col[e];
                        const float4e* xp = (const float4e*)(x + (size_t)c * HD + sub8 * 16);
                        a0 += xp[0];
                        a1 += xp[1];
                        a2 += xp[2];
                        a3 += xp[3];
                    }
                }
                a0 *= inv; a1 *= inv; a2 *= inv; a3 *= inv;
                uint4 o0, o1;
                o0.x = (unsigned int)f2bf(a0[0]) | ((unsigned int)f2bf(a0[1]) << 16);
                o0.y = (unsigned int)f2bf(a0[2]) | ((unsigned int)f2bf(a0[3]) << 16);
                o0.z = (unsigned int)f2bf(a1[0]) | ((unsigned int)f2bf(a1[1]) << 16);
                o0.w = (unsigned int)f2bf(a1[2]) | ((unsigned int)f2bf(a1[3]) << 16);
                o1.x = (unsigned int)f2bf(a2[0]) | ((unsigned int)f2bf(a2[1]) << 16);
                o1.y = (unsigned int)f2bf(a2[2]) | ((unsigned int)f2bf(a2[3]) << 16);
                o1.z = (unsigned int)f2bf(a3[0]) | ((unsigned int)f2bf(a3[1]) << 16);
                o1.w = (unsigned int)f2bf(a3[2]) | ((unsigned int)f2bf(a3[3]) << 16);
                const int ck0 = sub8 * 2;
                *(uint4*)&As[row * 128 + ((ck0 ^ (row & 15)) << 3)] = o0;
                *(uint4*)&As[row * 128 + (((ck0 + 1) ^ (row & 15)) << 3)] = o1;
            }
        } else {
            // root/self term: gather x row directly
#pragma unroll 1
            for (int half = 0; half < 2; half++) {
                const int row = grp + half * 64;
                const int dst = block0 + row;
                uint4 o0 = {0u, 0u, 0u, 0u}, o1 = {0u, 0u, 0u, 0u};
                if (dst < N) {
                    int srcn = HAS_IDX ? ids[dst] : dst;
                    const float* xp = x + (size_t)srcn * HD + sub8 * 16;
                    float4 v0 = *(const float4*)(xp);
                    float4 v1 = *(const float4*)(xp + 4);
                    float4 v2 = *(const float4*)(xp + 8);
                    float4 v3 = *(const float4*)(xp + 12);
                    o0.x = (unsigned int)f2bf(v0.x) | ((unsigned int)f2bf(v0.y) << 16);
                    o0.y = (unsigned int)f2bf(v0.z) | ((unsigned int)f2bf(v0.w) << 16);
                    o0.z = (unsigned int)f2bf(v1.x) | ((unsigned int)f2bf(v1.y) << 16);
                    o0.w = (unsigned int)f2bf(v1.z) | ((unsigned int)f2bf(v1.w) << 16);
                    o1.x = (unsigned int)f2bf(v2.x) | ((unsigned int)f2bf(v2.y) << 16);
                    o1.y = (unsigned int)f2bf(v2.z) | ((unsigned int)f2bf(v2.w) << 16);
                    o1.z = (unsigned int)f2bf(v3.x) | ((unsigned int)f2bf(v3.y) << 16);
                    o1.w = (unsigned int)f2bf(v3.z) | ((unsigned int)f2bf(v3.w) << 16);
                }
                const int ck0 = sub8 * 2;
                *(uint4*)&As[row * 128 + ((ck0 ^ (row & 15)) << 3)] = o0;
                *(uint4*)&As[row * 128 + (((ck0 + 1) ^ (row & 15)) << 3)] = o1;
            }
        }
        __syncthreads();

        // ---- MFMA over the staged tiles ----
#pragma unroll
        for (int k0 = 0; k0 < 4; k0++) {
            short8 af[4], bf[2];
#pragma unroll
            for (int rt = 0; rt < 4; rt++) {
                int m = rowbase + rt * 16 + ln15;
                int ck = k0 * 4 + quad;
                af[rt] = *(const short8*)&As[m * 128 + ((ck ^ (m & 15)) << 3)];
            }
#pragma unroll
            for (int ct = 0; ct < 2; ct++) {
                int n = colbase + ct * 16 + ln15;
                int ck = k0 * 4 + quad;
                bf[ct] = *(const short8*)&Ws[n * 128 + ((ck ^ (n & 15)) << 3)];
            }
#pragma unroll
            for (int rt = 0; rt < 4; rt++)
#pragma unroll
                for (int ct = 0; ct < 2; ct++)
                    acc[rt][ct] = __builtin_amdgcn_mfma_f32_16x16x32_bf16(
                        af[rt], bf[ct], acc[rt][ct], 0, 0, 0);
        }
        __syncthreads();
    }

#pragma unroll
    for (int ct = 0; ct < 2; ct++) {
        int ncol = colbase + ct * 16 + ln15;
        float bv = bias[ncol];
#pragma unroll
        for (int rt = 0; rt < 4; rt++) {
#pragma unroll
            for (int rg = 0; rg < 4; rg++) {
                int rowg = block0 + rowbase + rt * 16 + quad * 4 + rg;
                if (rowg < N) {
                    float v = acc[rt][ct][rg] + bv;
                    v = (ACT == 0) ? fmaxf(v, 0.0f) : (1.0f / (1.0f + expf(-v)));
                    Cout[(size_t)rowg * HD + ncol] = v;
                }
            }
        }
    }
}

extern "C" void kernel_launch(void* const* d_in, const int* in_sizes, int n_in,
                              void* d_out, int out_size, void* d_ws, size_t ws_size,
                              hipStream_t stream) {
    const int*   x_ids = (const int*)d_in[0];
    const int*   ei    = (const int*)d_in[1];
    const int*   et    = (const int*)d_in[2];
    const float* emb   = (const float*)d_in[3];
    const float* W1    = (const float*)d_in[4];
    const float* root1 = (const float*)d_in[5];
    const float* b1    = (const float*)d_in[6];
    const float* W2    = (const float*)d_in[7];
    const float* root2 = (const float*)d_in[8];
    const float* b2    = (const float*)d_in[9];

    const int N = in_sizes[0];
    const int E = in_sizes[1] / 2;
    const int NS = RNUM * N;
    float* out = (float*)d_out;

    // ---- arenas: row_start, col, colE, bsum, WT, z; cur aliases z (CSR build only) ----
    char* ws = (char*)d_ws;
    size_t off = 0;
    int* row_start = (int*)(ws + off); off += (size_t)NS * 4;                 // 3.2 MB
    int* col       = (int*)(ws + off); off += (size_t)E * 4;                  // 2.0 MB
    int* colE      = (int*)(ws + off); off += (size_t)E * 4;                  // 2.0 MB
    int* bsum      = (int*)(ws + off); off += 4096;
    unsigned short* WT = (unsigned short*)(ws + off); off += (size_t)18 * 16384 * 2;
    float* z       = (float*)(ws + off); off += (size_t)N * HD * 4;           // 51.2 MB
    int* cur       = (int*)z;   // alias: cur dead before z is first written

    const int scanBlocks = (NS + SCAN_BS - 1) / SCAN_BS;
    const int layerGrid = (N + 127) / 128;

    // ---- CSR build ----
    zero_i<<<(NS + 255) / 256, 256, 0, stream>>>(cur, NS);
    count_kernel<<<(E + 255) / 256, 256, 0, stream>>>(ei, et, cur, E, N);
    scan1<<<scanBlocks, 256, 0, stream>>>(cur, row_start, bsum, NS);
    scan2<<<1, 512, 0, stream>>>(bsum, scanBlocks);
    scan3<<<scanBlocks, 256, 0, stream>>>(row_start, cur, bsum, NS);
    fill_kernel<<<(E + 255) / 256, 256, 0, stream>>>(ei, et, x_ids, cur, col, colE, E, N);

    // ---- weights -> bf16 transposed: layer1 [0..8], layer2 [9..17] ----
    wt_kernel<<<(8 * 16384 + 255) / 256, 256, 0, stream>>>(W1, WT, 8);
    wt_kernel<<<(1 * 16384 + 255) / 256, 256, 0, stream>>>(root1, WT + 8 * 16384, 1);
    wt_kernel<<<(8 * 16384 + 255) / 256, 256, 0, stream>>>(W2, WT + 9 * 16384, 8);
    wt_kernel<<<(1 * 16384 + 255) / 256, 256, 0, stream>>>(root2, WT + 17 * 16384, 1);

    // ---- layer 1: z = relu(agg(emb[ids]) + emb[ids]@root1 + b1) ----
    rgcn_fused<true, 0><<<layerGrid, 512, 0, stream>>>(
        row_start, colE, x_ids, emb, WT, b1, z, N, E);
    // ---- layer 2: out = sigmoid(agg(z) + z@root2 + b2) ----
    rgcn_fused<false, 1><<<layerGrid, 512, 0, stream>>>(
        row_start, col, nullptr, z, WT + 9 * 16384, b2, out, N, E);
}